// Round 6
// baseline (283.074 us; speedup 1.0000x reference)
//
#include <hip/hip_runtime.h>

// CRF NLL: B=256, S=2048, T=64.
// Sequence-parallel forward algorithm, KC=128 chunks/batch, WARM=48 warmup
// steps (Birkhoff contraction fixes direction; V_c = chunk log-scale growth;
// logZ = sum_c V_c + final lse). Denominator all-to-all in the matrix engine:
// per step Y(64x16) = E^T(64x64) x Q(64x16) via 8x mfma_f32_16x16x32_f16, E^T
// persistent in VGPRs; feedback is pure cvt_pkrtz (D's per-lane tag set == B's
// required tag set).
//
// Round-5 post-mortem: ~3150 cyc/step vs ~800 accounted -> chain/stall bound at
// 1 wave/SIMD (zero TLP; streams==waves), with likely AGPR-copy tax (need ~145
// VGPR, compiler chose 100). This revision:
//   - KC 64->128: steps/stream 80->64; 2048 den waves = 2/SIMD TLP.
//   - STALE-SCALE renorm: this step's power-of-2 scale comes from the PREVIOUS
//     step's shfl (exact bookkeeping: esum tracks the exponent actually
//     applied; the V_c formula is invariant to which power-of-2 is chosen;
//     f16 range absorbs the 1-step drift). Removes ds_bpermute + scale-wait
//     from the per-step critical chain; exact syncs only at the warm/main
//     boundary and the end. x*sc fused pre-MFMA: one post-MFMA mul.
//   - __launch_bounds__(64,2): 256-VGPR budget (rule: 512/(arg2*waves/block)),
//     fits ring-4+A+tf without AGPR shuffling, still allows 2 waves/SIMD.
// Numerator: 256 dedicated gather-waves, unchanged.
#define BB 256
#define SS 2048
#define TT 64
#define KC 128
#define LC 16               // main steps per chunk
#define WARM 48
#define NSTEP (WARM + LC)   // 64 steps per stream (last OOB-predicated)
#define DEN_WAVES (BB * 8)  // 2048 denominator waves (16 streams each)
#define NSLOT 128
#define SLOT_STRIDE 32      // floats; slots 128 B apart
#define LN2 0.69314718055994531f
#define LOG2E 1.4426950408889634f

typedef __fp16 half2v __attribute__((ext_vector_type(2)));
typedef __fp16 half8v __attribute__((ext_vector_type(8)));
typedef float float4v __attribute__((ext_vector_type(4)));

__device__ __forceinline__ float4v mfma16(half8v a, half8v b, float4v c) {
  return __builtin_amdgcn_mfma_f32_16x16x32_f16(a, b, c, 0, 0, 0);
}

__global__ __launch_bounds__(64, 2) void crf_kernel(
    const float* __restrict__ em, const float* __restrict__ startT,
    const float* __restrict__ endT, const float* __restrict__ trans,
    const int* __restrict__ tags, const int* __restrict__ mask,
    float* __restrict__ acc, int slotmask) {
  const int lane = threadIdx.x;

  if (blockIdx.x >= DEN_WAVES) {
    // ---------------- numerator: one wave per batch, pure gathers ----------
    const int bb = blockIdx.x - DEN_WAVES;
    const int* tg = tags + bb * SS;
    const int* mp = mask + bb * SS;
    const float* emb = em + (size_t)bb * SS * TT;
    float part = 0.f;
    int cnt = 0;
#pragma unroll 4
    for (int k = 0; k < SS / 64; ++k) {
      int i = k * 64 + lane;
      int m = mp[i];
      cnt += m;
      if (i >= 1 && m) {
        int t1 = tg[i], t0 = tg[i - 1];
        part += trans[t0 * TT + t1] + emb[(size_t)i * TT + t1];
      }
    }
#pragma unroll
    for (int o = 32; o > 0; o >>= 1) {
      part += __shfl_xor(part, o, 64);
      cnt += __shfl_xor(cnt, o, 64);
    }
    if (lane == 0) {
      int t0 = tg[0];
      float num = part + startT[t0] + emb[t0] + endT[tg[cnt - 1]];
      atomicAdd(acc + (size_t)(blockIdx.x & slotmask) * SLOT_STRIDE,
                -num * (1.0f / BB));
    }
    return;
  }

  // ---------------- denominator: 16 streams per wave via MFMA --------------
  // XCD-grouped swizzle: physical wg w -> XCD w%8; XCD x gets the contiguous
  // logical range [x*256, x*256+256) = 32 whole batches (8 waves per batch).
  const int w = blockIdx.x;
  const int L = (w & 7) * (DEN_WAVES / 8) + (w >> 3);
  const int bb = L >> 3;           // batch (8 waves per batch at KC=128)
  const int s = lane & 15;         // stream column
  const int g = lane >> 4;         // k-group / row-group
  const int c = (L & 7) * 16 + s;  // this lane's stream = chunk index
  const float* emB = em + (size_t)bb * SS * TT;
  const size_t rowb = (size_t)bb * SS;

  // A fragments: E^T, A[mt][kt][e] = exp(trans[k][m])*2^-5,
  // k = 32kt + 16(e>>2) + 4g + (e&3), m = 16mt + s.
  half8v A[4][2];
#pragma unroll
  for (int mt = 0; mt < 4; ++mt)
#pragma unroll
    for (int kt = 0; kt < 2; ++kt) {
      half8v f;
#pragma unroll
      for (int e = 0; e < 8; e += 2) {
        int k0 = 32 * kt + 16 * (e >> 2) + 4 * g + (e & 3);
        int m = 16 * mt + s;
        float v0 = __expf(trans[k0 * TT + m]) * 0.03125f;
        float v1 = __expf(trans[(k0 + 1) * TT + m]) * 0.03125f;
        half2v p = __builtin_amdgcn_cvt_pkrtz(v0, v1);
        f[e] = p[0];
        f[e + 1] = p[1];
      }
      A[mt][kt] = f;
    }

  // state: q as B-fragments (f16), tag = 32kt + 16(e>>2) + 4g + (e&3)
  half8v B0, B1;
#pragma unroll
  for (int e = 0; e < 8; ++e) {
    B0[e] = (__fp16)0.015625f;  // uniform 2^-6; warmup fixes direction
    B1[e] = (__fp16)0.015625f;
  }
  // v_ready = published tag-0 value of the PREVIOUS step (shfl result,
  // consumed one step late -> bpermute latency off the critical chain).
  float v_ready = 0.015625f;
  int esum = 0, nsteps = 0;
  float sS = 0.f, gamma = 0.f;
  float4v tf0, tf1, tf2, tf3;

  const int base = c * LC - WARM + 1;

  // ring of 4 step-buffers: slot k holds emissions for step idx, idx%4==k
  float4v buf[4][4];

  auto PF = [&](int slot, int idx) {
    int p = base + idx;
    p = p < 0 ? 0 : (p > SS - 1 ? SS - 1 : p);  // clamp; boundary garbage is
    const float* r = emB + (size_t)p * TT + 4 * g;  // discarded/predicated
#pragma unroll
    for (int mt = 0; mt < 4; ++mt) buf[slot][mt] = *(const float4v*)(r + 16 * mt);
  };
  auto CORE = [&](const float4v (&x)[4]) {
    // stale scale: sc = f(q0 of previous step); exact exponent bookkeeping
    int eb = __builtin_bit_cast(int, v_ready) & 0x7f800000;
    float sc = __builtin_bit_cast(float, 0x7C000000 - eb);  // 2^(121-e)
    esum += eb >> 23;
    nsteps += 1;
    float4v xs0 = x[0] * sc, xs1 = x[1] * sc, xs2 = x[2] * sc, xs3 = x[3] * sc;
    const float4v z = {0.f, 0.f, 0.f, 0.f};
    tf0 = mfma16(A[0][0], B0, z);
    tf0 = mfma16(A[0][1], B1, tf0);
    tf1 = mfma16(A[1][0], B0, z);
    tf1 = mfma16(A[1][1], B1, tf1);
    tf2 = mfma16(A[2][0], B0, z);
    tf2 = mfma16(A[2][1], B1, tf2);
    tf3 = mfma16(A[3][0], B0, z);
    tf3 = mfma16(A[3][1], B1, tf3);
    tf0 *= xs0; tf1 *= xs1; tf2 *= xs2; tf3 *= xs3;
    v_ready = __shfl(tf0[0], s, 64);  // consumed next step (pipelined)
    half2v p;
    p = __builtin_amdgcn_cvt_pkrtz(tf0[0], tf0[1]); B0[0] = p[0]; B0[1] = p[1];
    p = __builtin_amdgcn_cvt_pkrtz(tf0[2], tf0[3]); B0[2] = p[0]; B0[3] = p[1];
    p = __builtin_amdgcn_cvt_pkrtz(tf1[0], tf1[1]); B0[4] = p[0]; B0[5] = p[1];
    p = __builtin_amdgcn_cvt_pkrtz(tf1[2], tf1[3]); B0[6] = p[0]; B0[7] = p[1];
    p = __builtin_amdgcn_cvt_pkrtz(tf2[0], tf2[1]); B1[0] = p[0]; B1[1] = p[1];
    p = __builtin_amdgcn_cvt_pkrtz(tf2[2], tf2[3]); B1[2] = p[0]; B1[3] = p[1];
    p = __builtin_amdgcn_cvt_pkrtz(tf3[0], tf3[1]); B1[4] = p[0]; B1[5] = p[1];
    p = __builtin_amdgcn_cvt_pkrtz(tf3[2], tf3[3]); B1[6] = p[0]; B1[7] = p[1];
  };
  auto STEP = [&](int slot, int pfIdx, bool doPf) {
    float4v x[4];
#pragma unroll
    for (int mt = 0; mt < 4; ++mt)
#pragma unroll
      for (int e = 0; e < 4; ++e) x[mt][e] = __expf(buf[slot][mt][e]);
    if (doPf) PF(slot, pfIdx);
    CORE(x);
  };

  // prologue: fill ring with steps 0..3
#pragma unroll
  for (int k = 0; k < 4; ++k) PF(k, k);

  for (int idx = 0; idx < WARM; idx += 4) {  // steps 0..47
#pragma unroll
    for (int k = 0; k < 4; ++k) STEP(k, idx + k + 4, true);
  }

  // main-region boundary (after step 47): exact sync on the in-flight shfl
  {
    float q0b = v_ready;  // q0 after step 47 (exact)
    sS = __log2f(q0b) + (float)(6 + esum - 116 * nsteps);
    if (c == 0) {  // exact init from alpha_0 (per-lane predicated, no x-lane)
      float aref = startT[0] + emB[0];
      gamma = aref * LOG2E;
      sS = 0.f;
      esum = 0;
      nsteps = 0;
      v_ready = 0.015625f;  // reset pipeline ref: q0 = 2^-6 exactly
#pragma unroll
      for (int e = 0; e < 8; ++e) {
        int t0i = 16 * (e >> 2) + 4 * g + (e & 3);
        B0[e] = (__fp16)(__expf(startT[t0i] + emB[t0i] - aref) * 0.015625f);
        B1[e] = (__fp16)(__expf(startT[t0i + 32] + emB[t0i + 32] - aref) *
                         0.015625f);
      }
    }
  }

  for (int idx = WARM; idx < NSTEP - 4; idx += 4) {  // steps 48..59
#pragma unroll
    for (int k = 0; k < 4; ++k) STEP(k, idx + k + 4, true);  // pf up to 63
  }
  // steps 60..62 (always in range: p <= c*16+15 <= 2047)
  STEP(0, 0, false);
  STEP(1, 0, false);
  STEP(2, 0, false);
  // step 63: OOB for chunk 127 (p=2048) — convergent compute, predicated commit
  float qf;
  {
    half8v oB0 = B0, oB1 = B1;
    float4v o0 = tf0, o1 = tf1, o2 = tf2, o3 = tf3;
    int oes = esum, on = nsteps;
    float ov = v_ready;  // q0 after step 62 (exact; waits shfl_62)
    STEP(3, 0, false);
    int p = base + (NSTEP - 1);
    int pc = p > SS - 1 ? SS - 1 : p;
    bool act = (p >= 1) && (p <= SS - 1) && (mask[rowb + pc] != 0);
    qf = act ? v_ready : ov;  // final exact q0 (waits shfl_63)
    if (!act) {
      B0 = oB0; B1 = oB1; esum = oes; nsteps = on;
      tf0 = o0; tf1 = o1; tf2 = o2; tf3 = o3;
    }
  }

  // chunk contribution: V_c = ln2 * (eS - sS)
  float eS = __log2f(qf) + (float)(6 + esum - 116 * nsteps) + gamma;
  float contrib = LN2 * (eS - sS);

  // final logsumexp (only c==KC-1 streams use it; computed convergently)
  {
    float q0l = __log2f(qf);
    float4v ar0, ar1, ar2, ar3;
    float mx = -1e30f;
#pragma unroll
    for (int r = 0; r < 4; ++r) {
      ar0[r] = LN2 * (__log2f(tf0[r]) - q0l) + endT[4 * g + r];
      ar1[r] = LN2 * (__log2f(tf1[r]) - q0l) + endT[16 + 4 * g + r];
      ar2[r] = LN2 * (__log2f(tf2[r]) - q0l) + endT[32 + 4 * g + r];
      ar3[r] = LN2 * (__log2f(tf3[r]) - q0l) + endT[48 + 4 * g + r];
      mx = fmaxf(mx, fmaxf(fmaxf(ar0[r], ar1[r]), fmaxf(ar2[r], ar3[r])));
    }
    mx = fmaxf(mx, __shfl_xor(mx, 16, 64));
    mx = fmaxf(mx, __shfl_xor(mx, 32, 64));
    float ex = 0.f;
#pragma unroll
    for (int r = 0; r < 4; ++r)
      ex += __expf(ar0[r] - mx) + __expf(ar1[r] - mx) + __expf(ar2[r] - mx) +
            __expf(ar3[r] - mx);
    ex += __shfl_xor(ex, 16, 64);
    ex += __shfl_xor(ex, 32, 64);
    if (c == KC - 1) contrib += mx + __logf(ex);
  }

  // one atomic per wave: sum contribs of the 16 streams (g==0 lanes only)
  float val = (g == 0) ? contrib : 0.f;
#pragma unroll
  for (int o = 32; o > 0; o >>= 1) val += __shfl_xor(val, o, 64);
  if (lane == 0)
    atomicAdd(acc + (size_t)(blockIdx.x & slotmask) * SLOT_STRIDE,
              val * (1.0f / BB));
}

__global__ __launch_bounds__(64) void reduce_kernel(const float* __restrict__ ws,
                                                    float* __restrict__ out) {
  float v = ws[(size_t)threadIdx.x * SLOT_STRIDE] +
            ws[(size_t)(threadIdx.x + 64) * SLOT_STRIDE];
#pragma unroll
  for (int o = 32; o > 0; o >>= 1) v += __shfl_xor(v, o, 64);
  if (threadIdx.x == 0) *out = v;
}

extern "C" void kernel_launch(void* const* d_in, const int* in_sizes, int n_in,
                              void* d_out, int out_size, void* d_ws, size_t ws_size,
                              hipStream_t stream) {
  const float* em = (const float*)d_in[0];
  const float* startT = (const float*)d_in[1];
  const float* endT = (const float*)d_in[2];
  const float* trans = (const float*)d_in[3];
  const int* tags = (const int*)d_in[4];
  const int* mask = (const int*)d_in[5];
  float* out = (float*)d_out;

  const size_t need = (size_t)NSLOT * SLOT_STRIDE * sizeof(float);
  if (d_ws && ws_size >= need) {
    (void)hipMemsetAsync(d_ws, 0, need, stream);
    crf_kernel<<<DEN_WAVES + BB, 64, 0, stream>>>(em, startT, endT, trans, tags,
                                                  mask, (float*)d_ws, NSLOT - 1);
    reduce_kernel<<<1, 64, 0, stream>>>((const float*)d_ws, out);
  } else {  // tiny-workspace fallback: single accumulator
    (void)hipMemsetAsync(out, 0, sizeof(float), stream);
    crf_kernel<<<DEN_WAVES + BB, 64, 0, stream>>>(em, startT, endT, trans, tags,
                                                  mask, out, 0);
  }
}

// Round 7
// 250.742 us; speedup vs baseline: 1.1289x; 1.1289x over previous
//
#include <hip/hip_runtime.h>

// CRF NLL: B=256, S=2048, T=64.
// Sequence-parallel forward algorithm, KC=64 chunks/batch, WARM=48 warmup
// steps (Birkhoff contraction fixes direction; V_c = chunk log-scale growth;
// logZ = sum_c V_c + final lse). Denominator all-to-all in the matrix engine:
// per step Y(64x16) = E^T(64x64) x Q(64x16) via 8x mfma_f32_16x16x32_f16, E^T
// persistent in VGPRs; feedback is pure cvt_pkrtz (D's per-lane tag set == B's
// required tag set). Stale-scale renorm (r6): the power-of-2 scale comes from
// the previous step's shfl; exact exponent bookkeeping, bpermute off-chain.
//
// Round-6 post-mortem: demand throughput scales with waves (2.5/3.2/4.0 TB/s
// at 768/1024/2048 waves) == Little's-law latency ramp with ~1 KB in flight
// per wave -> the compiler SANK the ring-4 prefetch loads to their use point
// (VGPR_Count 96-112 < the ~140 needed for a live ring), collapsing the
// pipeline to depth 1; every step pays ~800-cyc memory latency. This rev:
//   - sched_barrier(0) fences around each PF: loads pinned at issue site,
//     ring really in flight (16 KB/wave), backend emits counted vmcnt.
//   - __launch_bounds__(64,1): 512-VGPR budget, no pressure motive to sink.
//   - KC=64 (NSTEP=80, 1024 den waves = 1/SIMD): lowest HBM floor (~197 MB)
//     among full-SIMD-coverage configs.
// Numerator: 256 dedicated gather-waves, unchanged.
#define BB 256
#define SS 2048
#define TT 64
#define KC 64
#define LC 32               // main steps per chunk
#define WARM 48
#define NSTEP (WARM + LC)   // 80 steps per stream (last OOB-predicated)
#define DEN_WAVES (BB * 4)  // 1024 denominator waves (16 streams each)
#define NSLOT 128
#define SLOT_STRIDE 32      // floats; slots 128 B apart
#define LN2 0.69314718055994531f
#define LOG2E 1.4426950408889634f

typedef __fp16 half2v __attribute__((ext_vector_type(2)));
typedef __fp16 half8v __attribute__((ext_vector_type(8)));
typedef float float4v __attribute__((ext_vector_type(4)));

__device__ __forceinline__ float4v mfma16(half8v a, half8v b, float4v c) {
  return __builtin_amdgcn_mfma_f32_16x16x32_f16(a, b, c, 0, 0, 0);
}

__global__ __launch_bounds__(64, 1) void crf_kernel(
    const float* __restrict__ em, const float* __restrict__ startT,
    const float* __restrict__ endT, const float* __restrict__ trans,
    const int* __restrict__ tags, const int* __restrict__ mask,
    float* __restrict__ acc, int slotmask) {
  const int lane = threadIdx.x;

  if (blockIdx.x >= DEN_WAVES) {
    // ---------------- numerator: one wave per batch, pure gathers ----------
    const int bb = blockIdx.x - DEN_WAVES;
    const int* tg = tags + bb * SS;
    const int* mp = mask + bb * SS;
    const float* emb = em + (size_t)bb * SS * TT;
    float part = 0.f;
    int cnt = 0;
#pragma unroll 4
    for (int k = 0; k < SS / 64; ++k) {
      int i = k * 64 + lane;
      int m = mp[i];
      cnt += m;
      if (i >= 1 && m) {
        int t1 = tg[i], t0 = tg[i - 1];
        part += trans[t0 * TT + t1] + emb[(size_t)i * TT + t1];
      }
    }
#pragma unroll
    for (int o = 32; o > 0; o >>= 1) {
      part += __shfl_xor(part, o, 64);
      cnt += __shfl_xor(cnt, o, 64);
    }
    if (lane == 0) {
      int t0 = tg[0];
      float num = part + startT[t0] + emb[t0] + endT[tg[cnt - 1]];
      atomicAdd(acc + (size_t)(blockIdx.x & slotmask) * SLOT_STRIDE,
                -num * (1.0f / BB));
    }
    return;
  }

  // ---------------- denominator: 16 streams per wave via MFMA --------------
  // XCD-grouped swizzle: physical wg w -> XCD w%8; XCD x gets the contiguous
  // logical range [x*128, x*128+128) = 32 whole batches (4 waves per batch).
  const int w = blockIdx.x;
  const int L = (w & 7) * (DEN_WAVES / 8) + (w >> 3);
  const int bb = L >> 2;           // batch (4 waves per batch at KC=64)
  const int s = lane & 15;         // stream column
  const int g = lane >> 4;         // k-group / row-group
  const int c = (L & 3) * 16 + s;  // this lane's stream = chunk index
  const float* emB = em + (size_t)bb * SS * TT;
  const size_t rowb = (size_t)bb * SS;

  // A fragments: E^T, A[mt][kt][e] = exp(trans[k][m])*2^-5,
  // k = 32kt + 16(e>>2) + 4g + (e&3), m = 16mt + s.
  half8v A[4][2];
#pragma unroll
  for (int mt = 0; mt < 4; ++mt)
#pragma unroll
    for (int kt = 0; kt < 2; ++kt) {
      half8v f;
#pragma unroll
      for (int e = 0; e < 8; e += 2) {
        int k0 = 32 * kt + 16 * (e >> 2) + 4 * g + (e & 3);
        int m = 16 * mt + s;
        float v0 = __expf(trans[k0 * TT + m]) * 0.03125f;
        float v1 = __expf(trans[(k0 + 1) * TT + m]) * 0.03125f;
        half2v p = __builtin_amdgcn_cvt_pkrtz(v0, v1);
        f[e] = p[0];
        f[e + 1] = p[1];
      }
      A[mt][kt] = f;
    }

  // state: q as B-fragments (f16), tag = 32kt + 16(e>>2) + 4g + (e&3)
  half8v B0, B1;
#pragma unroll
  for (int e = 0; e < 8; ++e) {
    B0[e] = (__fp16)0.015625f;  // uniform 2^-6; warmup fixes direction
    B1[e] = (__fp16)0.015625f;
  }
  // v_ready = published tag-0 value of the PREVIOUS step (shfl result,
  // consumed one step late -> bpermute latency off the critical chain).
  float v_ready = 0.015625f;
  int esum = 0, nsteps = 0;
  float sS = 0.f, gamma = 0.f;
  float4v tf0, tf1, tf2, tf3;

  const int base = c * LC - WARM + 1;

  // ring of 4 step-buffers: slot k holds emissions for step idx, idx%4==k
  float4v buf[4][4];

  auto PF = [&](int slot, int idx) {
    int p = base + idx;
    p = p < 0 ? 0 : (p > SS - 1 ? SS - 1 : p);  // clamp; boundary garbage is
    const float* r = emB + (size_t)p * TT + 4 * g;  // discarded/predicated
    // Fences pin the 4 loads HERE: the machine scheduler may not sink them
    // toward their use (which collapsed the pipeline in r4-r6).
    __builtin_amdgcn_sched_barrier(0);
#pragma unroll
    for (int mt = 0; mt < 4; ++mt) buf[slot][mt] = *(const float4v*)(r + 16 * mt);
    __builtin_amdgcn_sched_barrier(0);
  };
  auto CORE = [&](const float4v (&x)[4]) {
    // stale scale: sc = f(q0 of previous step); exact exponent bookkeeping
    int eb = __builtin_bit_cast(int, v_ready) & 0x7f800000;
    float sc = __builtin_bit_cast(float, 0x7C000000 - eb);  // 2^(121-e)
    esum += eb >> 23;
    nsteps += 1;
    float4v xs0 = x[0] * sc, xs1 = x[1] * sc, xs2 = x[2] * sc, xs3 = x[3] * sc;
    const float4v z = {0.f, 0.f, 0.f, 0.f};
    tf0 = mfma16(A[0][0], B0, z);
    tf0 = mfma16(A[0][1], B1, tf0);
    tf1 = mfma16(A[1][0], B0, z);
    tf1 = mfma16(A[1][1], B1, tf1);
    tf2 = mfma16(A[2][0], B0, z);
    tf2 = mfma16(A[2][1], B1, tf2);
    tf3 = mfma16(A[3][0], B0, z);
    tf3 = mfma16(A[3][1], B1, tf3);
    tf0 *= xs0; tf1 *= xs1; tf2 *= xs2; tf3 *= xs3;
    v_ready = __shfl(tf0[0], s, 64);  // consumed next step (pipelined)
    half2v p;
    p = __builtin_amdgcn_cvt_pkrtz(tf0[0], tf0[1]); B0[0] = p[0]; B0[1] = p[1];
    p = __builtin_amdgcn_cvt_pkrtz(tf0[2], tf0[3]); B0[2] = p[0]; B0[3] = p[1];
    p = __builtin_amdgcn_cvt_pkrtz(tf1[0], tf1[1]); B0[4] = p[0]; B0[5] = p[1];
    p = __builtin_amdgcn_cvt_pkrtz(tf1[2], tf1[3]); B0[6] = p[0]; B0[7] = p[1];
    p = __builtin_amdgcn_cvt_pkrtz(tf2[0], tf2[1]); B1[0] = p[0]; B1[1] = p[1];
    p = __builtin_amdgcn_cvt_pkrtz(tf2[2], tf2[3]); B1[2] = p[0]; B1[3] = p[1];
    p = __builtin_amdgcn_cvt_pkrtz(tf3[0], tf3[1]); B1[4] = p[0]; B1[5] = p[1];
    p = __builtin_amdgcn_cvt_pkrtz(tf3[2], tf3[3]); B1[6] = p[0]; B1[7] = p[1];
  };
  auto STEP = [&](int slot, int pfIdx, bool doPf) {
    float4v x[4];
#pragma unroll
    for (int mt = 0; mt < 4; ++mt)
#pragma unroll
      for (int e = 0; e < 4; ++e) x[mt][e] = __expf(buf[slot][mt][e]);
    if (doPf) PF(slot, pfIdx);
    CORE(x);
  };

  // prologue: fill ring with steps 0..3
#pragma unroll
  for (int k = 0; k < 4; ++k) PF(k, k);

  for (int idx = 0; idx < WARM; idx += 4) {  // steps 0..47
#pragma unroll
    for (int k = 0; k < 4; ++k) STEP(k, idx + k + 4, true);
  }

  // main-region boundary (after step 47): exact sync on the in-flight shfl
  {
    float q0b = v_ready;  // q0 after step 47 (exact)
    sS = __log2f(q0b) + (float)(6 + esum - 116 * nsteps);
    if (c == 0) {  // exact init from alpha_0 (per-lane predicated, no x-lane)
      float aref = startT[0] + emB[0];
      gamma = aref * LOG2E;
      sS = 0.f;
      esum = 0;
      nsteps = 0;
      v_ready = 0.015625f;  // reset pipeline ref: q0 = 2^-6 exactly
#pragma unroll
      for (int e = 0; e < 8; ++e) {
        int t0i = 16 * (e >> 2) + 4 * g + (e & 3);
        B0[e] = (__fp16)(__expf(startT[t0i] + emB[t0i] - aref) * 0.015625f);
        B1[e] = (__fp16)(__expf(startT[t0i + 32] + emB[t0i + 32] - aref) *
                         0.015625f);
      }
    }
  }

  for (int idx = WARM; idx < NSTEP - 4; idx += 4) {  // steps 48..75
#pragma unroll
    for (int k = 0; k < 4; ++k) STEP(k, idx + k + 4, true);  // pf up to 79
  }
  // steps 76..78 (always in range: p <= c*32+31 <= 2047)
  STEP(0, 0, false);
  STEP(1, 0, false);
  STEP(2, 0, false);
  // step 79: OOB for chunk 63 (p=2048) — convergent compute, predicated commit
  float qf;
  {
    half8v oB0 = B0, oB1 = B1;
    float4v o0 = tf0, o1 = tf1, o2 = tf2, o3 = tf3;
    int oes = esum, on = nsteps;
    float ov = v_ready;  // q0 after step 78 (exact)
    STEP(3, 0, false);
    int p = base + (NSTEP - 1);
    int pc = p > SS - 1 ? SS - 1 : p;
    bool act = (p >= 1) && (p <= SS - 1) && (mask[rowb + pc] != 0);
    qf = act ? v_ready : ov;  // final exact q0
    if (!act) {
      B0 = oB0; B1 = oB1; esum = oes; nsteps = on;
      tf0 = o0; tf1 = o1; tf2 = o2; tf3 = o3;
    }
  }

  // chunk contribution: V_c = ln2 * (eS - sS)
  float eS = __log2f(qf) + (float)(6 + esum - 116 * nsteps) + gamma;
  float contrib = LN2 * (eS - sS);

  // final logsumexp (only c==KC-1 streams use it; computed convergently)
  {
    float q0l = __log2f(qf);
    float4v ar0, ar1, ar2, ar3;
    float mx = -1e30f;
#pragma unroll
    for (int r = 0; r < 4; ++r) {
      ar0[r] = LN2 * (__log2f(tf0[r]) - q0l) + endT[4 * g + r];
      ar1[r] = LN2 * (__log2f(tf1[r]) - q0l) + endT[16 + 4 * g + r];
      ar2[r] = LN2 * (__log2f(tf2[r]) - q0l) + endT[32 + 4 * g + r];
      ar3[r] = LN2 * (__log2f(tf3[r]) - q0l) + endT[48 + 4 * g + r];
      mx = fmaxf(mx, fmaxf(fmaxf(ar0[r], ar1[r]), fmaxf(ar2[r], ar3[r])));
    }
    mx = fmaxf(mx, __shfl_xor(mx, 16, 64));
    mx = fmaxf(mx, __shfl_xor(mx, 32, 64));
    float ex = 0.f;
#pragma unroll
    for (int r = 0; r < 4; ++r)
      ex += __expf(ar0[r] - mx) + __expf(ar1[r] - mx) + __expf(ar2[r] - mx) +
            __expf(ar3[r] - mx);
    ex += __shfl_xor(ex, 16, 64);
    ex += __shfl_xor(ex, 32, 64);
    if (c == KC - 1) contrib += mx + __logf(ex);
  }

  // one atomic per wave: sum contribs of the 16 streams (g==0 lanes only)
  float val = (g == 0) ? contrib : 0.f;
#pragma unroll
  for (int o = 32; o > 0; o >>= 1) val += __shfl_xor(val, o, 64);
  if (lane == 0)
    atomicAdd(acc + (size_t)(blockIdx.x & slotmask) * SLOT_STRIDE,
              val * (1.0f / BB));
}

__global__ __launch_bounds__(64) void reduce_kernel(const float* __restrict__ ws,
                                                    float* __restrict__ out) {
  float v = ws[(size_t)threadIdx.x * SLOT_STRIDE] +
            ws[(size_t)(threadIdx.x + 64) * SLOT_STRIDE];
#pragma unroll
  for (int o = 32; o > 0; o >>= 1) v += __shfl_xor(v, o, 64);
  if (threadIdx.x == 0) *out = v;
}

extern "C" void kernel_launch(void* const* d_in, const int* in_sizes, int n_in,
                              void* d_out, int out_size, void* d_ws, size_t ws_size,
                              hipStream_t stream) {
  const float* em = (const float*)d_in[0];
  const float* startT = (const float*)d_in[1];
  const float* endT = (const float*)d_in[2];
  const float* trans = (const float*)d_in[3];
  const int* tags = (const int*)d_in[4];
  const int* mask = (const int*)d_in[5];
  float* out = (float*)d_out;

  const size_t need = (size_t)NSLOT * SLOT_STRIDE * sizeof(float);
  if (d_ws && ws_size >= need) {
    (void)hipMemsetAsync(d_ws, 0, need, stream);
    crf_kernel<<<DEN_WAVES + BB, 64, 0, stream>>>(em, startT, endT, trans, tags,
                                                  mask, (float*)d_ws, NSLOT - 1);
    reduce_kernel<<<1, 64, 0, stream>>>((const float*)d_ws, out);
  } else {  // tiny-workspace fallback: single accumulator
    (void)hipMemsetAsync(out, 0, sizeof(float), stream);
    crf_kernel<<<DEN_WAVES + BB, 64, 0, stream>>>(em, startT, endT, trans, tags,
                                                  mask, out, 0);
  }
}